// Round 1
// baseline (858.530 us; speedup 1.0000x reference)
//
#include <hip/hip_runtime.h>
#include <hip/hip_bf16.h>

#define BB 4
#define SS 512
#define DD 512
#define HH 8
#define DK 64
#define PP 16
#define TSZ 33   // 2P+1

// ---------------- table mean ----------------
__global__ void tmean_kernel(const float* __restrict__ rel_table, float* __restrict__ Tm) {
    int t = threadIdx.x;
    if (t < TSZ) {
        float s = 0.f;
        for (int e = 0; e < DK; ++e) s += rel_table[t * DK + e];
        Tm[t] = s * (1.f / DK);
    }
}

// ---------------- QKV projection: out[b,h,s,dk] = X @ W^T + b ----------------
__global__ void proj_kernel(const float* __restrict__ X, const float* __restrict__ W,
                            const float* __restrict__ bias, float* __restrict__ out_bhsd) {
    __shared__ float xs[16][16];
    __shared__ float ws[16][17];
    int tx = threadIdx.x, ty = threadIdx.y;
    int row = blockIdx.y * 16 + ty;   // [0,2048)
    int col = blockIdx.x * 16 + tx;   // [0,512)
    float acc = 0.f;
    for (int k0 = 0; k0 < DD; k0 += 16) {
        xs[ty][tx] = X[row * DD + k0 + tx];
        ws[ty][tx] = W[(blockIdx.x * 16 + ty) * DD + k0 + tx];
        __syncthreads();
#pragma unroll
        for (int kk = 0; kk < 16; ++kk) acc += xs[ty][kk] * ws[tx][kk];
        __syncthreads();
    }
    acc += bias[col];
    int b = row >> 9, i = row & (SS - 1);
    int h = col >> 6, dki = col & (DK - 1);
    out_bhsd[((b * HH + h) * SS + i) * DK + dki] = acc;
}

// ---------------- scores = Q K^T / sqrt(dk), per (b,h) ----------------
__global__ void scores_kernel(const float* __restrict__ Q, const float* __restrict__ K,
                              float* __restrict__ scores) {
    int bh = blockIdx.z;
    const float* Qb = Q + (size_t)bh * SS * DK;
    const float* Kb = K + (size_t)bh * SS * DK;
    __shared__ float qs[16][17];
    __shared__ float ks[16][17];
    int tx = threadIdx.x, ty = threadIdx.y;
    int i = blockIdx.y * 16 + ty, j = blockIdx.x * 16 + tx;
    float acc = 0.f;
    for (int k0 = 0; k0 < DK; k0 += 16) {
        qs[ty][tx] = Qb[(blockIdx.y * 16 + ty) * DK + k0 + tx];
        ks[ty][tx] = Kb[(blockIdx.x * 16 + ty) * DK + k0 + tx];
        __syncthreads();
#pragma unroll
        for (int kk = 0; kk < 16; ++kk) acc += qs[ty][kk] * ks[tx][kk];
        __syncthreads();
    }
    scores[((size_t)bh * SS + i) * SS + j] = acc * 0.125f;
}

// ---------------- scores += sum_d Q[b,h,i,d] * Tmean[clip(rel)+P] ----------------
// block: fixed (b,i), 64 j's; 256 threads = 4 threads per j (16 d's each)
__global__ void relbias_kernel(const float* __restrict__ Q, const int* __restrict__ relpos,
                               const float* __restrict__ Tm, float* __restrict__ scores) {
    int b = blockIdx.z;
    int i = blockIdx.y;
    int j0 = blockIdx.x * 64;
    __shared__ float tmean[TSZ];
    __shared__ float qrow[DD];  // [h][d]
    int t = threadIdx.x;
    if (t < TSZ) tmean[t] = Tm[t];
    for (int o = t; o < DD; o += 256) {
        int h = o >> 6, d = o & (DK - 1);
        qrow[o] = Q[((b * HH + h) * SS + i) * DK + d];
    }
    __syncthreads();
    int jl = t >> 2, qq = t & 3;
    int j = j0 + jl;
    const int* ip = relpos + (((size_t)(b * SS + i) * SS + j) * DK) + qq * 16;
    float tv[16];
#pragma unroll
    for (int kk = 0; kk < 16; ++kk) {
        int r = ip[kk];
        r = min(max(r, -PP), PP) + PP;
        tv[kk] = tmean[r];
    }
#pragma unroll
    for (int h = 0; h < HH; ++h) {
        float p = 0.f;
#pragma unroll
        for (int kk = 0; kk < 16; ++kk) p += qrow[h * DK + qq * 16 + kk] * tv[kk];
        p += __shfl_xor(p, 1);
        p += __shfl_xor(p, 2);
        if (qq == 0) scores[((size_t)(b * HH + h) * SS + i) * SS + j] += p;
    }
}

// ---------------- masked softmax over j (in place), row per block ----------------
__global__ void softmax_kernel(float* __restrict__ attn, const int* __restrict__ mask) {
    int bhi = blockIdx.x;                // [0, 32*512)
    int b = bhi >> 12;
    float* row = attn + (size_t)bhi * SS;
    int t = threadIdx.x;
    float v0 = row[t];
    float v1 = row[t + 256];
    if (mask[b * SS + t] == 0) v0 = -1e9f;
    if (mask[b * SS + t + 256] == 0) v1 = -1e9f;

    __shared__ float red[4];
    float m = fmaxf(v0, v1);
#pragma unroll
    for (int off = 32; off >= 1; off >>= 1) m = fmaxf(m, __shfl_xor(m, off));
    if ((t & 63) == 0) red[t >> 6] = m;
    __syncthreads();
    float mall = fmaxf(fmaxf(red[0], red[1]), fmaxf(red[2], red[3]));
    __syncthreads();

    float e0 = expf(v0 - mall);
    float e1 = expf(v1 - mall);
    float s = e0 + e1;
#pragma unroll
    for (int off = 32; off >= 1; off >>= 1) s += __shfl_xor(s, off);
    if ((t & 63) == 0) red[t >> 6] = s;
    __syncthreads();
    float sall = red[0] + red[1] + red[2] + red[3];
    float inv = 1.f / sall;
    row[t] = e0 * inv;
    row[t + 256] = e1 * inv;
}

// ---------------- ctx[b,i, h*64+dk] = attn @ V, per (b,h) ----------------
__global__ void ctx_kernel(const float* __restrict__ attn, const float* __restrict__ V,
                           float* __restrict__ ctx_bsd) {
    int bh = blockIdx.z;
    int b = bh >> 3, h = bh & 7;
    __shared__ float as[16][17];
    __shared__ float vs[16][17];
    int tx = threadIdx.x, ty = threadIdx.y;
    int i = blockIdx.y * 16 + ty;
    int dkc = blockIdx.x * 16 + tx;
    float acc = 0.f;
    for (int k0 = 0; k0 < SS; k0 += 16) {
        as[ty][tx] = attn[((size_t)bh * SS + i) * SS + k0 + tx];
        vs[ty][tx] = V[((size_t)bh * SS + k0 + ty) * DK + blockIdx.x * 16 + tx];
        __syncthreads();
#pragma unroll
        for (int kk = 0; kk < 16; ++kk) acc += as[ty][kk] * vs[kk][tx];
        __syncthreads();
    }
    ctx_bsd[(b * SS + i) * DD + h * DK + dkc] = acc;
}

// ---------------- x = ctx @ Wo^T + bo + query (residual) ----------------
__global__ void outproj_kernel(const float* __restrict__ Xc, const float* __restrict__ Wo,
                               const float* __restrict__ bo, const float* __restrict__ query,
                               float* __restrict__ xres) {
    __shared__ float xs[16][16];
    __shared__ float ws[16][17];
    int tx = threadIdx.x, ty = threadIdx.y;
    int row = blockIdx.y * 16 + ty;
    int col = blockIdx.x * 16 + tx;
    float acc = 0.f;
    for (int k0 = 0; k0 < DD; k0 += 16) {
        xs[ty][tx] = Xc[row * DD + k0 + tx];
        ws[ty][tx] = Wo[(blockIdx.x * 16 + ty) * DD + k0 + tx];
        __syncthreads();
#pragma unroll
        for (int kk = 0; kk < 16; ++kk) acc += xs[ty][kk] * ws[tx][kk];
        __syncthreads();
    }
    xres[row * DD + col] = acc + bo[col] + query[row * DD + col];
}

// ---------------- LayerNorm over last dim (512) ----------------
__global__ void ln_kernel(const float* __restrict__ x, const float* __restrict__ gamma,
                          const float* __restrict__ beta, float* __restrict__ y) {
    int r = blockIdx.x;  // [0,2048)
    int t = threadIdx.x; // 256
    float v0 = x[r * DD + t];
    float v1 = x[r * DD + t + 256];
    __shared__ float red[4];
    float s = v0 + v1;
#pragma unroll
    for (int off = 32; off >= 1; off >>= 1) s += __shfl_xor(s, off);
    if ((t & 63) == 0) red[t >> 6] = s;
    __syncthreads();
    float mu = (red[0] + red[1] + red[2] + red[3]) * (1.f / DD);
    __syncthreads();
    float d0 = v0 - mu, d1 = v1 - mu;
    float sq = d0 * d0 + d1 * d1;
#pragma unroll
    for (int off = 32; off >= 1; off >>= 1) sq += __shfl_xor(sq, off);
    if ((t & 63) == 0) red[t >> 6] = sq;
    __syncthreads();
    float var = (red[0] + red[1] + red[2] + red[3]) * (1.f / DD);
    float inv = rsqrtf(var + 1e-5f);
    y[r * DD + t] = d0 * inv * gamma[t] + beta[t];
    y[r * DD + t + 256] = d1 * inv * gamma[t + 256] + beta[t + 256];
}

extern "C" void kernel_launch(void* const* d_in, const int* in_sizes, int n_in,
                              void* d_out, int out_size, void* d_ws, size_t ws_size,
                              hipStream_t stream) {
    const float* query  = (const float*)d_in[0];
    const float* key    = (const float*)d_in[1];
    const float* value  = (const float*)d_in[2];
    const float* Wq     = (const float*)d_in[3];
    const float* bq     = (const float*)d_in[4];
    const float* Wk     = (const float*)d_in[5];
    const float* bk     = (const float*)d_in[6];
    const float* Wv     = (const float*)d_in[7];
    const float* bv     = (const float*)d_in[8];
    const float* Wo     = (const float*)d_in[9];
    const float* bo     = (const float*)d_in[10];
    const float* rtab   = (const float*)d_in[11];
    const float* gamma  = (const float*)d_in[12];
    const float* beta   = (const float*)d_in[13];
    const int*   mask   = (const int*)d_in[14];
    const int*   relpos = (const int*)d_in[15];

    float* out = (float*)d_out;
    float* y    = out;                        // [4,512,512]
    float* attn = out + (size_t)BB * SS * DD; // [4,8,512,512] — also scores scratch

    float* ws   = (float*)d_ws;
    float* Tm   = ws;                                  // 64
    float* Qb   = ws + 64;                             // 1,048,576
    float* Kb   = Qb + (size_t)BB * HH * SS * DK;
    float* Vb   = Kb + (size_t)BB * HH * SS * DK;
    float* ctx  = Vb + (size_t)BB * HH * SS * DK;      // [b,s,D]
    float* xres = ctx + (size_t)BB * SS * DD;

    hipLaunchKernelGGL(tmean_kernel, dim3(1), dim3(64), 0, stream, rtab, Tm);

    dim3 gblk(16, 16);
    dim3 gproj(DD / 16, (BB * SS) / 16);
    hipLaunchKernelGGL(proj_kernel, gproj, gblk, 0, stream, query, Wq, bq, Qb);
    hipLaunchKernelGGL(proj_kernel, gproj, gblk, 0, stream, key,   Wk, bk, Kb);
    hipLaunchKernelGGL(proj_kernel, gproj, gblk, 0, stream, value, Wv, bv, Vb);

    hipLaunchKernelGGL(scores_kernel, dim3(SS / 16, SS / 16, BB * HH), gblk, 0, stream,
                       Qb, Kb, attn);

    hipLaunchKernelGGL(relbias_kernel, dim3(SS / 64, SS, BB), dim3(256), 0, stream,
                       Qb, relpos, Tm, attn);

    hipLaunchKernelGGL(softmax_kernel, dim3(BB * HH * SS), dim3(256), 0, stream, attn, mask);

    hipLaunchKernelGGL(ctx_kernel, dim3(DK / 16, SS / 16, BB * HH), gblk, 0, stream,
                       attn, Vb, ctx);

    hipLaunchKernelGGL(outproj_kernel, gproj, gblk, 0, stream, ctx, Wo, bo, query, xres);

    hipLaunchKernelGGL(ln_kernel, dim3(BB * SS), dim3(256), 0, stream, xres, gamma, beta, y);
}

// Round 2
// 580.996 us; speedup vs baseline: 1.4777x; 1.4777x over previous
//
#include <hip/hip_runtime.h>
#include <hip/hip_bf16.h>

#define BB 4
#define SS 512
#define DD 512
#define HH 8
#define DK 64
#define PP 16
#define TSZ 33   // 2P+1

typedef __bf16 bf16x8 __attribute__((ext_vector_type(8)));
typedef float  f32x4  __attribute__((ext_vector_type(4)));

__device__ inline bf16x8 cvt8(const float* __restrict__ p) {
    f32x4 a = *(const f32x4*)p;
    f32x4 b = *(const f32x4*)(p + 4);
    bf16x8 r;
    r[0] = (__bf16)a[0]; r[1] = (__bf16)a[1]; r[2] = (__bf16)a[2]; r[3] = (__bf16)a[3];
    r[4] = (__bf16)b[0]; r[5] = (__bf16)b[1]; r[6] = (__bf16)b[2]; r[7] = (__bf16)b[3];
    return r;
}

// ---------------- table mean ----------------
__global__ void tmean_kernel(const float* __restrict__ rel_table, float* __restrict__ Tm) {
    int t = threadIdx.x;
    if (t < TSZ) {
        float s = 0.f;
        for (int e = 0; e < DK; ++e) s += rel_table[t * DK + e];
        Tm[t] = s * (1.f / DK);
    }
}

// ---------------- QKV projection (MFMA): C = X @ W^T + b, bf16 out ----------------
// mode 0: out[b,h,s,dk] ; mode 1: out[b,h,dk,s] (transposed, for V)
__global__ void proj_mfma_kernel(const float* __restrict__ X, const float* __restrict__ W,
                                 const float* __restrict__ bias, __bf16* __restrict__ out,
                                 int mode) {
    int lane = threadIdx.x;           // 0..63
    int wave = threadIdx.y;           // 0..3
    int tm = blockIdx.y * 4 + wave;   // 16-row tile index, [0,128)
    int tn = blockIdx.x;              // 16-col tile index, [0,32)
    int m = lane & 15, quad = lane >> 4;

    const float* arow = X + (size_t)(tm * 16 + m) * DD + quad * 8;
    const float* brow = W + (size_t)(tn * 16 + m) * DD + quad * 8;

    f32x4 acc = {0.f, 0.f, 0.f, 0.f};
    for (int k0 = 0; k0 < DD; k0 += 32) {
        bf16x8 a = cvt8(arow + k0);
        bf16x8 b = cvt8(brow + k0);
        acc = __builtin_amdgcn_mfma_f32_16x16x32_bf16(a, b, acc, 0, 0, 0);
    }

    int col = tn * 16 + m;
    int h = col >> 6, dk = col & (DK - 1);
    float bv = bias[col];
#pragma unroll
    for (int r = 0; r < 4; ++r) {
        int rowg = tm * 16 + quad * 4 + r;
        int b = rowg >> 9, i = rowg & (SS - 1);
        float v = acc[r] + bv;
        if (mode == 0)
            out[((size_t)(b * HH + h) * SS + i) * DK + dk] = (__bf16)v;
        else
            out[((size_t)(b * HH + h) * DK + dk) * SS + i] = (__bf16)v;
    }
}

// ---------------- scores = Q K^T / sqrt(dk) (MFMA), f32 out ----------------
__global__ void scores_mfma_kernel(const __bf16* __restrict__ Q, const __bf16* __restrict__ K,
                                   float* __restrict__ scores) {
    int bh = blockIdx.z;
    int lane = threadIdx.x, wave = threadIdx.y;
    int tm = blockIdx.y * 4 + wave;   // [0,32)
    int tn = blockIdx.x;              // [0,32)
    int m = lane & 15, quad = lane >> 4;

    const __bf16* qrow = Q + ((size_t)bh * SS + tm * 16 + m) * DK + quad * 8;
    const __bf16* krow = K + ((size_t)bh * SS + tn * 16 + m) * DK + quad * 8;

    f32x4 acc = {0.f, 0.f, 0.f, 0.f};
#pragma unroll
    for (int k0 = 0; k0 < DK; k0 += 32) {
        bf16x8 a = *(const bf16x8*)(qrow + k0);
        bf16x8 b = *(const bf16x8*)(krow + k0);
        acc = __builtin_amdgcn_mfma_f32_16x16x32_bf16(a, b, acc, 0, 0, 0);
    }

    int col = tn * 16 + m;
#pragma unroll
    for (int r = 0; r < 4; ++r) {
        int rowg = tm * 16 + quad * 4 + r;
        scores[((size_t)bh * SS + rowg) * SS + col] = acc[r] * 0.125f;
    }
}

// ---------------- scores += sum_d Q[b,h,i,d] * Tmean[clip(rel)+P] ----------------
__global__ void relbias_kernel(const __bf16* __restrict__ Q, const int* __restrict__ relpos,
                               const float* __restrict__ Tm, float* __restrict__ scores) {
    int b = blockIdx.z;
    int i = blockIdx.y;
    int j0 = blockIdx.x * 64;
    __shared__ float tmean[TSZ];
    __shared__ float qrow[DD];  // [h][d]
    int t = threadIdx.x;
    if (t < TSZ) tmean[t] = Tm[t];
    for (int o = t; o < DD; o += 256) {
        int h = o >> 6, d = o & (DK - 1);
        qrow[o] = (float)Q[((size_t)(b * HH + h) * SS + i) * DK + d];
    }
    __syncthreads();
    int jl = t >> 2, qq = t & 3;
    int j = j0 + jl;
    const int4* ip4 = (const int4*)(relpos + (((size_t)(b * SS + i) * SS + j) * DK) + qq * 16);
    int4 w0 = ip4[0], w1 = ip4[1], w2 = ip4[2], w3 = ip4[3];
    int rr[16] = {w0.x, w0.y, w0.z, w0.w, w1.x, w1.y, w1.z, w1.w,
                  w2.x, w2.y, w2.z, w2.w, w3.x, w3.y, w3.z, w3.w};
    float tv[16];
#pragma unroll
    for (int kk = 0; kk < 16; ++kk) {
        int r = min(max(rr[kk], -PP), PP) + PP;
        tv[kk] = tmean[r];
    }
#pragma unroll
    for (int h = 0; h < HH; ++h) {
        float p = 0.f;
#pragma unroll
        for (int kk = 0; kk < 16; ++kk) p += qrow[h * DK + qq * 16 + kk] * tv[kk];
        p += __shfl_xor(p, 1);
        p += __shfl_xor(p, 2);
        if (qq == 0) scores[((size_t)(b * HH + h) * SS + i) * SS + j] += p;
    }
}

// ---------------- masked softmax over j (in place) ----------------
__global__ void softmax_kernel(float* __restrict__ attn, const int* __restrict__ mask) {
    int bhi = blockIdx.x;                // [0, 32*512)
    int b = bhi >> 12;
    float* row = attn + (size_t)bhi * SS;
    int t = threadIdx.x;
    float v0 = row[t];
    float v1 = row[t + 256];
    if (mask[b * SS + t] == 0) v0 = -1e9f;
    if (mask[b * SS + t + 256] == 0) v1 = -1e9f;

    __shared__ float red[4];
    float m = fmaxf(v0, v1);
#pragma unroll
    for (int off = 32; off >= 1; off >>= 1) m = fmaxf(m, __shfl_xor(m, off));
    if ((t & 63) == 0) red[t >> 6] = m;
    __syncthreads();
    float mall = fmaxf(fmaxf(red[0], red[1]), fmaxf(red[2], red[3]));
    __syncthreads();

    float e0 = expf(v0 - mall);
    float e1 = expf(v1 - mall);
    float s = e0 + e1;
#pragma unroll
    for (int off = 32; off >= 1; off >>= 1) s += __shfl_xor(s, off);
    if ((t & 63) == 0) red[t >> 6] = s;
    __syncthreads();
    float sall = red[0] + red[1] + red[2] + red[3];
    float inv = 1.f / sall;
    row[t] = e0 * inv;
    row[t + 256] = e1 * inv;
}

// ---------------- ctx = attn @ V (MFMA), bf16 out [b,s,D] ----------------
// A = attn f32 [bh,i,j] (converted in-kernel), B = Vt bf16 [bh,dk,j]
__global__ void ctx_mfma_kernel(const float* __restrict__ attn, const __bf16* __restrict__ Vt,
                                __bf16* __restrict__ ctx_bsd) {
    int bh = blockIdx.z;
    int bb = bh >> 3, h = bh & 7;
    int lane = threadIdx.x, wave = threadIdx.y;
    int tm = blockIdx.y * 4 + wave;   // i tile [0,32)
    int tn = blockIdx.x;              // d tile [0,4)
    int m = lane & 15, quad = lane >> 4;

    const float*  arow = attn + ((size_t)bh * SS + tm * 16 + m) * SS + quad * 8;
    const __bf16* brow = Vt + ((size_t)bh * DK + tn * 16 + m) * SS + quad * 8;

    f32x4 acc = {0.f, 0.f, 0.f, 0.f};
    for (int k0 = 0; k0 < SS; k0 += 32) {
        bf16x8 a = cvt8(arow + k0);
        bf16x8 b = *(const bf16x8*)(brow + k0);
        acc = __builtin_amdgcn_mfma_f32_16x16x32_bf16(a, b, acc, 0, 0, 0);
    }

    int d = tn * 16 + m;
#pragma unroll
    for (int r = 0; r < 4; ++r) {
        int i = tm * 16 + quad * 4 + r;
        ctx_bsd[((size_t)(bb * SS + i)) * DD + h * DK + d] = (__bf16)acc[r];
    }
}

// ---------------- x = ctx @ Wo^T + bo + query (MFMA), f32 out ----------------
__global__ void outproj_mfma_kernel(const __bf16* __restrict__ Xc, const float* __restrict__ Wo,
                                    const float* __restrict__ bo, const float* __restrict__ query,
                                    float* __restrict__ xres) {
    int lane = threadIdx.x, wave = threadIdx.y;
    int tm = blockIdx.y * 4 + wave;   // [0,128)
    int tn = blockIdx.x;              // [0,32)
    int m = lane & 15, quad = lane >> 4;

    const __bf16* arow = Xc + (size_t)(tm * 16 + m) * DD + quad * 8;
    const float*  brow = Wo + (size_t)(tn * 16 + m) * DD + quad * 8;

    f32x4 acc = {0.f, 0.f, 0.f, 0.f};
    for (int k0 = 0; k0 < DD; k0 += 32) {
        bf16x8 a = *(const bf16x8*)(arow + k0);
        bf16x8 b = cvt8(brow + k0);
        acc = __builtin_amdgcn_mfma_f32_16x16x32_bf16(a, b, acc, 0, 0, 0);
    }

    int col = tn * 16 + m;
    float bv = bo[col];
#pragma unroll
    for (int r = 0; r < 4; ++r) {
        int rowg = tm * 16 + quad * 4 + r;
        xres[(size_t)rowg * DD + col] = acc[r] + bv + query[(size_t)rowg * DD + col];
    }
}

// ---------------- LayerNorm over last dim (512) ----------------
__global__ void ln_kernel(const float* __restrict__ x, const float* __restrict__ gamma,
                          const float* __restrict__ beta, float* __restrict__ y) {
    int r = blockIdx.x;  // [0,2048)
    int t = threadIdx.x; // 256
    float v0 = x[r * DD + t];
    float v1 = x[r * DD + t + 256];
    __shared__ float red[4];
    float s = v0 + v1;
#pragma unroll
    for (int off = 32; off >= 1; off >>= 1) s += __shfl_xor(s, off);
    if ((t & 63) == 0) red[t >> 6] = s;
    __syncthreads();
    float mu = (red[0] + red[1] + red[2] + red[3]) * (1.f / DD);
    __syncthreads();
    float d0 = v0 - mu, d1 = v1 - mu;
    float sq = d0 * d0 + d1 * d1;
#pragma unroll
    for (int off = 32; off >= 1; off >>= 1) sq += __shfl_xor(sq, off);
    if ((t & 63) == 0) red[t >> 6] = sq;
    __syncthreads();
    float var = (red[0] + red[1] + red[2] + red[3]) * (1.f / DD);
    float inv = rsqrtf(var + 1e-5f);
    y[r * DD + t] = d0 * inv * gamma[t] + beta[t];
    y[r * DD + t + 256] = d1 * inv * gamma[t + 256] + beta[t + 256];
}

extern "C" void kernel_launch(void* const* d_in, const int* in_sizes, int n_in,
                              void* d_out, int out_size, void* d_ws, size_t ws_size,
                              hipStream_t stream) {
    const float* query  = (const float*)d_in[0];
    const float* key    = (const float*)d_in[1];
    const float* value  = (const float*)d_in[2];
    const float* Wq     = (const float*)d_in[3];
    const float* bq     = (const float*)d_in[4];
    const float* Wk     = (const float*)d_in[5];
    const float* bk     = (const float*)d_in[6];
    const float* Wv     = (const float*)d_in[7];
    const float* bv     = (const float*)d_in[8];
    const float* Wo     = (const float*)d_in[9];
    const float* bo     = (const float*)d_in[10];
    const float* rtab   = (const float*)d_in[11];
    const float* gamma  = (const float*)d_in[12];
    const float* beta   = (const float*)d_in[13];
    const int*   mask   = (const int*)d_in[14];
    const int*   relpos = (const int*)d_in[15];

    float* out = (float*)d_out;
    float* y    = out;                        // [4,512,512]
    float* attn = out + (size_t)BB * SS * DD; // [4,8,512,512] — also scores scratch

    char* wsb = (char*)d_ws;
    float*  Tm    = (float*)wsb;                       wsb += 256;
    __bf16* Qbf   = (__bf16*)wsb;                      wsb += (size_t)BB * HH * SS * DK * 2;
    __bf16* Kbf   = (__bf16*)wsb;                      wsb += (size_t)BB * HH * SS * DK * 2;
    __bf16* Vtbf  = (__bf16*)wsb;                      wsb += (size_t)BB * HH * DK * SS * 2;
    __bf16* ctxbf = (__bf16*)wsb;                      wsb += (size_t)BB * SS * DD * 2;
    float*  xres  = (float*)wsb;                       wsb += (size_t)BB * SS * DD * 4;

    hipLaunchKernelGGL(tmean_kernel, dim3(1), dim3(64), 0, stream, rtab, Tm);

    dim3 wblk(64, 4);
    dim3 gproj(DD / 16, (BB * SS) / 64);
    hipLaunchKernelGGL(proj_mfma_kernel, gproj, wblk, 0, stream, query, Wq, bq, Qbf, 0);
    hipLaunchKernelGGL(proj_mfma_kernel, gproj, wblk, 0, stream, key,   Wk, bk, Kbf, 0);
    hipLaunchKernelGGL(proj_mfma_kernel, gproj, wblk, 0, stream, value, Wv, bv, Vtbf, 1);

    hipLaunchKernelGGL(scores_mfma_kernel, dim3(SS / 16, SS / 64, BB * HH), wblk, 0, stream,
                       Qbf, Kbf, attn);

    hipLaunchKernelGGL(relbias_kernel, dim3(SS / 64, SS, BB), dim3(256), 0, stream,
                       Qbf, relpos, Tm, attn);

    hipLaunchKernelGGL(softmax_kernel, dim3(BB * HH * SS), dim3(256), 0, stream, attn, mask);

    hipLaunchKernelGGL(ctx_mfma_kernel, dim3(DK / 16, SS / 64, BB * HH), wblk, 0, stream,
                       attn, Vtbf, ctxbf);

    hipLaunchKernelGGL(outproj_mfma_kernel, gproj, wblk, 0, stream, ctxbf, Wo, bo, query, xres);

    hipLaunchKernelGGL(ln_kernel, dim3(BB * SS), dim3(256), 0, stream, xres, gamma, beta, y);
}